// Round 8
// baseline (544.816 us; speedup 1.0000x reference)
//
#include <hip/hip_runtime.h>
#include <hip/hip_bf16.h>
#include <stdint.h>

typedef __bf16 bf16_t;
typedef bf16_t bf16x8 __attribute__((ext_vector_type(8)));
typedef bf16_t bf16x4 __attribute__((ext_vector_type(4)));
typedef float  f32x4  __attribute__((ext_vector_type(4)));

#define B_  16
#define S_  1024
#define D_  1024
#define BS_ (B_ * S_)            // 16384
#define MAT_ (S_ * D_)           // 1048576 elems per batch matrix

#define BAR()   __builtin_amdgcn_s_barrier()
#define LGKM0() asm volatile("s_waitcnt lgkmcnt(0)" ::: "memory")
#define VMC2()  asm volatile("s_waitcnt vmcnt(2)" ::: "memory")

__device__ __forceinline__ void async_load16(const void* g, void* l) {
    __builtin_amdgcn_global_load_lds((__attribute__((address_space(1))) void*)(g),
                                     (__attribute__((address_space(3))) void*)(l),
                                     16, 0, 0);
}

// ---------------------------------------------------------------------------
// 128x128-tile pipelined GEMM, 64 KiB LDS -> 2 blocks/CU (round 8).
// C[m,n] = sum_k A[m,k]*B[n,k]   (B given K-contiguous / transposed)
//
// Round-8 thesis: R3-R7 proved no intra-block schedule edit moves the 43%
// MfmaUtil plateau — at 128 KiB LDS there is exactly 1 block/CU, all 8
// waves are barrier-lockstep, so the CU alternates {LDS-read phase ~2300
// cyc} then {MFMA phase ~3725 cyc} with ZERO pipe overlap (sum = measured
// 7650 cyc/K-tile).  m114: independent co-resident waves co-schedule MFMA
// and memory pipes (time = max, not sum).  Fix: 128x128 tiles -> 32 KiB
// per buffer -> 64 KiB total -> 2 independent blocks/CU whose phases
// drift anti-phase.  Per-CU work is invariant; only overlap changes.
//
// SPLIT=0: plain bf16, BK=64, (row&7)<<4 XOR swizzle (128B rows).
// SPLIT=1: 3-term Markidis hi/lo bf16, BK=32, ((row>>1)&3)<<4 (64B rows).
// OSP=1: C written as bf16 hi/lo pair.
// XS=1: G2, grid (8,8,16): XCD k owns batches {2k,2k+1}; bn-inner order
//       keeps the 4 MB B-panel (f2 hi+lo per batch) L2-resident.
// XS=2: dual, grid (8,8,32): b<16 -> (gAh,gBh)->Cf; b>=16 -> (gAl,gBl)
//       ->Cf+16*MAT_; 4 logical batches per XCD.
// XS=3: G1, grid (8,128,1): XCD k owns bm in [16k,16k+16); B = Wt (4 MB
//       hi+lo) L2-resident chip-wide.
// STATS=1: epilogue emits per-block softmax partials (8-way per axis).
//
// Schedule: merged 2-phase per K-tile (R7 proved ≡ 4-phase):
//   M1: reads {A-low-half + ALL B} || stage A(t+1)->ob; BAR; LGKM0;
//       setprio(1); MFMA half; setprio(0); BAR.
//   M2: reads {A-high-half}        || stage B(t+2)->rb (B region was fully
//       consumed+LGKM0'd in M1); BAR; LGKM0; setprio(1); MFMA half;
//       setprio(0); VMC2; BAR.
// vmcnt ledger: 4 loads/K-tile (2 A + 2 B); at tile t's VMC2 outstanding =
// A(t+1)x2 + B(t+2)x2; wait-to-2 forces A(t+1) (and older B(t+1)) complete
// before tile t+1's reads.  Tail stages clamp to NT-1.  Program order
// reads -> stage -> BAR (R3 lesson).  Swizzle both-sides (rule 21).
// ---------------------------------------------------------------------------
template <int SPLIT, int OSP, int XS, int STATS>
__global__ __launch_bounds__(512, 4)
void gemm8p(const bf16_t* __restrict__ gAh, const bf16_t* __restrict__ gAl,
            const bf16_t* __restrict__ gBh, const bf16_t* __restrict__ gBl,
            float* __restrict__ Cf, bf16_t* __restrict__ Ch, bf16_t* __restrict__ Cl,
            float* __restrict__ Mp2, float* __restrict__ Zp2,
            float* __restrict__ Np2, float* __restrict__ Yp2,
            int M, int N, int K, long sA, long sB, long sC)
{
    (void)M;
    constexpr int BK  = SPLIT ? 32 : 64;
    constexpr int BUF = 32768;
    __shared__ __attribute__((aligned(16))) char smem[2 * BUF];   // 64 KiB

    const int tid  = threadIdx.x;
    const int w    = tid >> 6;
    const int lane = tid & 63;
    const int wm   = w >> 2;            // 0..1  (row half of 128)
    const int wn   = w & 3;             // 0..3  (col quarter of 128)
    const int fm   = lane & 15;
    const int quad = lane >> 4;

    int bm, bn, b;
    if constexpr (XS == 1) {
        // G2: grid (8,8,16) = 1024 blocks; XCD k owns batches {2k,2k+1}
        const int flat = (int)blockIdx.x + ((int)blockIdx.y << 3) + ((int)blockIdx.z << 6);
        const int xcd = flat & 7, slot = flat >> 3;      // slot in [0,128)
        b  = (xcd << 1) | (slot >> 6);
        const int rem = slot & 63;
        bm = rem >> 3;
        bn = rem & 7;
    } else if constexpr (XS == 2) {
        // dual: grid (8,8,32) = 2048 blocks; XCD k owns logical batches 4k..4k+3
        const int flat = (int)blockIdx.x + ((int)blockIdx.y << 3) + ((int)blockIdx.z << 6);
        const int xcd = flat & 7, slot = flat >> 3;      // slot in [0,256)
        b  = (xcd << 2) | (slot >> 6);
        const int rem = slot & 63;
        bm = rem >> 3;
        bn = rem & 7;
    } else if constexpr (XS == 3) {
        // G1: grid (8,128,1) = 1024 blocks; XCD k owns bm in [16k,16k+16)
        const int flat = (int)blockIdx.x + ((int)blockIdx.y << 3);
        const int xcd = flat & 7, slot = flat >> 3;      // slot in [0,128)
        b  = 0;
        bm = (xcd << 4) | (slot >> 3);
        bn = slot & 7;
    } else {
        bn = blockIdx.x; bm = blockIdx.y; b = blockIdx.z;
    }

    // operand select (DUAL)
    const bf16_t* pAh = gAh; const bf16_t* pAl = gAl;
    const bf16_t* pBh = gBh; const bf16_t* pBl = gBl;
    float* Cfp = Cf;
    if constexpr (XS == 2) {
        if (b >= 16) { pAh = gAl; pBh = gBl; Cfp = Cf + (long)B_ * MAT_; b -= 16; }
    }

    const int NT    = K / BK;
    const int abase = (int)((long)b * sA) + bm * 128 * K;
    const int bbase = (int)((long)b * sB) + bn * 128 * K;

    // ---- per-thread stage offsets (global elem offset sans k) --------------
    int aof[2], bof[2];
    if constexpr (!SPLIT) {
        // component tile [128][64] bf16 (128B rows); 2 chunks/thread (h).
#pragma unroll
        for (int h = 0; h < 2; ++h) {
            const int o   = h * 8192 + tid * 16;
            const int row = o >> 7;
            const int c   = ((o >> 4) & 7) ^ (row & 7);
            aof[h] = abase + row * K + c * 8;
            bof[h] = bbase + row * K + c * 8;
        }
    } else {
        // component tile [128][32] bf16 (64B rows); 1 chunk/thread.
        const int o   = tid * 16;
        const int row = o >> 6;
        const int c   = ((o >> 4) & 3) ^ ((row >> 1) & 3);
        aof[0] = abase + row * K + c * 8;
        bof[0] = bbase + row * K + c * 8;
        aof[1] = 0; bof[1] = 0;
    }

    f32x4 acc[4][2] = {};   // 4 m-frags x 2 n-frags (wave tile 64x32)

    if constexpr (!SPLIT) {
        // =========== plain bf16, BK=64; buf: A@0..16K, B@16K..32K =========
        auto stgA = [&](int t, int lb) {
            const int k = (t < NT ? t : NT - 1) * BK;
            async_load16(pAh + (aof[0] + k), smem + lb + tid * 16);
            async_load16(pAh + (aof[1] + k), smem + lb + 8192 + tid * 16);
        };
        auto stgB = [&](int t, int lb) {
            const int k = (t < NT ? t : NT - 1) * BK;
            async_load16(pBh + (bof[0] + k), smem + lb + 16384 + tid * 16);
            async_load16(pBh + (bof[1] + k), smem + lb + 24576 + tid * 16);
        };
        const int xb = (fm & 7) << 4;
        auto ldA = [&](int lb, int m, int ks) -> bf16x8 {
            const int row = wm * 64 + m * 16 + fm;
            return *(const bf16x8*)(smem + lb + row * 128 + ((ks * 64 + quad * 16) ^ xb));
        };
        auto ldB = [&](int lb, int n, int ks) -> bf16x8 {
            const int row = wn * 32 + n * 16 + fm;
            return *(const bf16x8*)(smem + lb + 16384 + row * 128 + ((ks * 64 + quad * 16) ^ xb));
        };

        bf16x8 ar[2][2], br[2][2];
        auto qp = [&](int mh) {
#pragma unroll
            for (int mm = 0; mm < 2; ++mm)
#pragma unroll
                for (int n = 0; n < 2; ++n) {
                    f32x4 c = acc[mh * 2 + mm][n];
                    c = __builtin_amdgcn_mfma_f32_16x16x32_bf16(ar[mm][0], br[n][0], c, 0, 0, 0);
                    c = __builtin_amdgcn_mfma_f32_16x16x32_bf16(ar[mm][1], br[n][1], c, 0, 0, 0);
                    acc[mh * 2 + mm][n] = c;
                }
        };

        stgA(0, 0); stgB(0, 0); stgB(1, BUF);       // 6 loads
        VMC2(); BAR();                               // tile0 resident

        const int NIT = NT >> 1;
        for (int it = 0; it < NIT; ++it) {
            const int t = it << 1;
#pragma unroll
            for (int ph = 0; ph < 2; ++ph) {
                const int rb = ph ? BUF : 0;
                const int ob = ph ? 0 : BUF;
                const int tt = t + ph;
                // M1: A-low + all B reads || stage A(t+1) -> ob
#pragma unroll
                for (int mm = 0; mm < 2; ++mm) { ar[mm][0] = ldA(rb, mm, 0); ar[mm][1] = ldA(rb, mm, 1); }
#pragma unroll
                for (int n = 0; n < 2; ++n) { br[n][0] = ldB(rb, n, 0); br[n][1] = ldB(rb, n, 1); }
                stgA(tt + 1, ob);
                BAR(); LGKM0(); __builtin_amdgcn_s_setprio(1);
                qp(0);
                __builtin_amdgcn_s_setprio(0); BAR();
                // M2: A-high reads || stage B(t+2) -> rb (B consumed in M1)
#pragma unroll
                for (int mm = 0; mm < 2; ++mm) { ar[mm][0] = ldA(rb, mm + 2, 0); ar[mm][1] = ldA(rb, mm + 2, 1); }
                stgB(tt + 2, rb);
                BAR(); LGKM0(); __builtin_amdgcn_s_setprio(1);
                qp(1);
                __builtin_amdgcn_s_setprio(0); VMC2(); BAR();
            }
        }
    } else {
        // ==== 3-term hi/lo, BK=32; buf: Ah@0, Al@8K, Bh@16K, Bl@24K ======
        auto stgAh = [&](int t, int lb) {
            const int k = (t < NT ? t : NT - 1) * BK;
            async_load16(pAh + (aof[0] + k), smem + lb + tid * 16);
        };
        auto stgAl = [&](int t, int lb) {
            const int k = (t < NT ? t : NT - 1) * BK;
            async_load16(pAl + (aof[0] + k), smem + lb + 8192 + tid * 16);
        };
        auto stgBh = [&](int t, int lb) {
            const int k = (t < NT ? t : NT - 1) * BK;
            async_load16(pBh + (bof[0] + k), smem + lb + 16384 + tid * 16);
        };
        auto stgBl = [&](int t, int lb) {
            const int k = (t < NT ? t : NT - 1) * BK;
            async_load16(pBl + (bof[0] + k), smem + lb + 24576 + tid * 16);
        };
        const int xs2 = ((fm >> 1) & 3) << 4;
        auto ldSA = [&](int lb, int comp, int m) -> bf16x8 {
            const int row = wm * 64 + m * 16 + fm;
            return *(const bf16x8*)(smem + lb + comp * 8192 + row * 64 + ((quad * 16) ^ xs2));
        };
        auto ldSB = [&](int lb, int comp, int n) -> bf16x8 {
            const int row = wn * 32 + n * 16 + fm;
            return *(const bf16x8*)(smem + lb + (2 + comp) * 8192 + row * 64 + ((quad * 16) ^ xs2));
        };

        bf16x8 arh[2], arl[2], brh[2], brl[2];
        auto qs = [&](int mh) {
#pragma unroll
            for (int mm = 0; mm < 2; ++mm)
#pragma unroll
                for (int n = 0; n < 2; ++n) {
                    f32x4 c = acc[mh * 2 + mm][n];
                    c = __builtin_amdgcn_mfma_f32_16x16x32_bf16(arh[mm], brh[n], c, 0, 0, 0);
                    c = __builtin_amdgcn_mfma_f32_16x16x32_bf16(arl[mm], brh[n], c, 0, 0, 0);
                    c = __builtin_amdgcn_mfma_f32_16x16x32_bf16(arh[mm], brl[n], c, 0, 0, 0);
                    acc[mh * 2 + mm][n] = c;
                }
        };

        stgAh(0, 0); stgAl(0, 0); stgBh(0, 0); stgBl(0, 0);
        stgBh(1, BUF); stgBl(1, BUF);               // 6 loads
        VMC2(); BAR();                               // tile0 resident

        const int NIT = NT >> 1;
        for (int it = 0; it < NIT; ++it) {
            const int t = it << 1;
#pragma unroll
            for (int ph = 0; ph < 2; ++ph) {
                const int rb = ph ? BUF : 0;
                const int ob = ph ? 0 : BUF;
                const int tt = t + ph;
                // M1: A-low + all B reads || stage Ah+Al(t+1) -> ob
#pragma unroll
                for (int mm = 0; mm < 2; ++mm) { arh[mm] = ldSA(rb, 0, mm); arl[mm] = ldSA(rb, 1, mm); }
#pragma unroll
                for (int n = 0; n < 2; ++n) { brh[n] = ldSB(rb, 0, n); brl[n] = ldSB(rb, 1, n); }
                stgAh(tt + 1, ob); stgAl(tt + 1, ob);
                BAR(); LGKM0(); __builtin_amdgcn_s_setprio(1);
                qs(0);
                __builtin_amdgcn_s_setprio(0); BAR();
                // M2: A-high reads || stage Bh+Bl(t+2) -> rb
#pragma unroll
                for (int mm = 0; mm < 2; ++mm) { arh[mm] = ldSA(rb, 0, mm + 2); arl[mm] = ldSA(rb, 1, mm + 2); }
                stgBh(tt + 2, rb); stgBl(tt + 2, rb);
                BAR(); LGKM0(); __builtin_amdgcn_s_setprio(1);
                qs(1);
                __builtin_amdgcn_s_setprio(0); VMC2(); BAR();
            }
        }
    }

    // ---- softmax partials from registers (STATS) ---------------------------
    // After the final VMC2+barrier the only in-flight LDS writes are the 2
    // clamped B-stages into buf1's B region (>= BUF+16384); smem[0..6K) safe.
    float2* colp = (float2*)smem;               // [2 wm][128 col]   2 KB
    float2* rowp = (float2*)(smem + 2048);      // [4 wn][128 row]   4 KB
    if constexpr (STATS) {
#pragma unroll
        for (int n = 0; n < 2; ++n) {           // col partials over 128 rows
            float m = acc[0][n][0];
#pragma unroll
            for (int i = 0; i < 4; ++i)
#pragma unroll
                for (int r = 0; r < 4; ++r) m = fmaxf(m, acc[i][n][r]);
            float z = 0.f;
#pragma unroll
            for (int i = 0; i < 4; ++i)
#pragma unroll
                for (int r = 0; r < 4; ++r) z += __expf(acc[i][n][r] - m);
#pragma unroll
            for (int off = 16; off <= 32; off <<= 1) {   // merge across quads
                float mo = __shfl_xor(m, off), zo = __shfl_xor(z, off);
                float nm = fmaxf(m, mo);
                z = z * __expf(m - nm) + zo * __expf(mo - nm); m = nm;
            }
            if (quad == 0) colp[wm * 128 + wn * 32 + n * 16 + fm] = make_float2(m, z);
        }
#pragma unroll
        for (int i = 0; i < 4; ++i)             // row partials over 128 cols
#pragma unroll
            for (int r = 0; r < 4; ++r) {
                float m = fmaxf(acc[i][0][r], acc[i][1][r]);
                float z = __expf(acc[i][0][r] - m) + __expf(acc[i][1][r] - m);
#pragma unroll
                for (int off = 1; off <= 8; off <<= 1) { // merge across fm
                    float mo = __shfl_xor(m, off), zo = __shfl_xor(z, off);
                    float nm = fmaxf(m, mo);
                    z = z * __expf(m - nm) + zo * __expf(mo - nm); m = nm;
                }
                if (fm == 0)
                    rowp[wn * 128 + wm * 64 + i * 16 + quad * 4 + r] = make_float2(m, z);
            }
    }

    // ---- C write: D[row = quad*4 + r][col = fm] per 16x16 fragment ---------
#pragma unroll
    for (int i = 0; i < 4; ++i) {
        const int row0 = bm * 128 + wm * 64 + i * 16 + quad * 4;
#pragma unroll
        for (int j = 0; j < 2; ++j) {
            const int col = bn * 128 + wn * 32 + j * 16 + fm;
#pragma unroll
            for (int r = 0; r < 4; ++r) {
                const long idx = (long)b * sC + (long)(row0 + r) * N + col;
                const float v = acc[i][j][r];
                if constexpr (OSP) {
                    const bf16_t h = (bf16_t)v;
                    Ch[idx] = h;
                    Cl[idx] = (bf16_t)(v - (float)h);
                } else {
                    Cfp[idx] = v;
                }
            }
        }
    }

    if constexpr (STATS) {
        __syncthreads();
        if (tid < 128) {                        // merge cols across wm
            float2 p0 = colp[tid], p1 = colp[128 + tid];
            float nm = fmaxf(p0.x, p1.x);
            float z = p0.y * __expf(p0.x - nm) + p1.y * __expf(p1.x - nm);
            const int gcol = bn * 128 + tid;
            Mp2[((b * 8 + bm) << 10) + gcol] = nm;
            Zp2[((b * 8 + bm) << 10) + gcol] = z;
        } else if (tid < 256) {                 // merge rows across wn
            const int rr = tid - 128;
            float2 p = rowp[rr];
            float m = p.x, z = p.y;
#pragma unroll
            for (int c = 1; c < 4; ++c) {
                float2 q = rowp[c * 128 + rr];
                float nm = fmaxf(m, q.x);
                z = z * __expf(m - nm) + q.y * __expf(q.x - nm); m = nm;
            }
            const int grow = bm * 128 + rr;
            Np2[((b * 8 + bn) << 10) + grow] = m;
            Yp2[((b * 8 + bn) << 10) + grow] = z;
        }
    }
}

// ---------------------------------------------------------------------------
// fp32 -> bf16 hi/lo split for f1 and f2, plus W transpose-split, one launch.
// ---------------------------------------------------------------------------
__global__ void split_all(const float* __restrict__ f1, const float* __restrict__ f2,
                          const float* __restrict__ W,
                          bf16_t* __restrict__ h1, bf16_t* __restrict__ l1,
                          bf16_t* __restrict__ h2, bf16_t* __restrict__ l2,
                          bf16_t* __restrict__ Wth, bf16_t* __restrict__ Wtl)
{
    __shared__ float tile[32][33];
    const int bid = blockIdx.x;
    if (bid < 32768) {
        const long tot = (long)B_ * MAT_;
        long i = ((long)bid * 256 + threadIdx.x) * 4;
        const float* s; bf16_t* h; bf16_t* l;
        if (i < tot) { s = f1; h = h1; l = l1; }
        else { i -= tot; s = f2; h = h2; l = l2; }
        float4 v = *(const float4*)(s + i);
        float a[4] = {v.x, v.y, v.z, v.w};
        bf16x4 hh, ll;
#pragma unroll
        for (int e = 0; e < 4; ++e) {
            const bf16_t hv = (bf16_t)a[e];
            hh[e] = hv;
            ll[e] = (bf16_t)(a[e] - (float)hv);
        }
        *(bf16x4*)(h + i) = hh;
        *(bf16x4*)(l + i) = ll;
    } else {
        const int b2 = bid - 32768;
        const int d0 = (b2 & 31) * 32, e0 = (b2 >> 5) * 32;
        const int tx = threadIdx.x & 31, ty = threadIdx.x >> 5;
        for (int r = ty; r < 32; r += 8)
            tile[r][tx] = W[(long)(d0 + r) * D_ + e0 + tx];
        __syncthreads();
        for (int r = ty; r < 32; r += 8) {
            const float v = tile[tx][r];
            const bf16_t h = (bf16_t)v;
            Wth[(long)(e0 + r) * D_ + d0 + tx] = h;
            Wtl[(long)(e0 + r) * D_ + d0 + tx] = (bf16_t)(v - (float)h);
        }
    }
}

// ---------------------------------------------------------------------------
// Fused attention-matrix build (one pass over cc), with inline 8-way
// partial-combine:
//   attV[b,s,t] = exp(cc[b,s,t]-N[b,s]) / Y[b,s]        (same layout)
//   attA[b,t,s] = exp(cc[b,s,t]-M[b,t]) / Z[b,t]        (transposed)
// ---------------------------------------------------------------------------
__global__ void build_atts(const float* __restrict__ cc,
                           const float* __restrict__ Mp2, const float* __restrict__ Zp2,
                           const float* __restrict__ Np2, const float* __restrict__ Yp2,
                           bf16_t* __restrict__ attA, bf16_t* __restrict__ attV)
{
    __shared__ float tile[32][33];
    __shared__ float tm[32], tz[32], sm[32], sz[32];
    const int b = blockIdx.z;
    const int s0 = blockIdx.x * 32, t0 = blockIdx.y * 32;
    const int tx = threadIdx.x, ty = threadIdx.y;
    const int flat = ty * 32 + tx;

    if (flat < 32) {                            // t-stats (audio: over s)
        const int t = t0 + flat;
        float m = Mp2[((b * 8) << 10) + t], z = Zp2[((b * 8) << 10) + t];
#pragma unroll
        for (int c = 1; c < 8; ++c) {
            float mc = Mp2[((b * 8 + c) << 10) + t];
            float zc = Zp2[((b * 8 + c) << 10) + t];
            float nm = fmaxf(m, mc);
            z = z * __expf(m - nm) + zc * __expf(mc - nm); m = nm;
        }
        tm[flat] = m; tz[flat] = 1.f / z;
    } else if (flat < 64) {                     // s-stats (visual: over t)
        const int ii = flat - 32;
        const int s = s0 + ii;
        float m = Np2[((b * 8) << 10) + s], z = Yp2[((b * 8) << 10) + s];
#pragma unroll
        for (int c = 1; c < 8; ++c) {
            float mc = Np2[((b * 8 + c) << 10) + s];
            float zc = Yp2[((b * 8 + c) << 10) + s];
            float nm = fmaxf(m, mc);
            z = z * __expf(m - nm) + zc * __expf(mc - nm); m = nm;
        }
        sm[ii] = m; sz[ii] = 1.f / z;
    }
    __syncthreads();

    const float* src = cc + (long)b * MAT_;
    bf16_t* dV = attV + (long)b * MAT_;
    bf16_t* dA = attA + (long)b * MAT_;
    for (int r = ty; r < 32; r += 8) {
        const int s = s0 + r;
        const float v = src[(long)s * S_ + t0 + tx];
        tile[r][tx] = v;
        dV[(long)s * S_ + t0 + tx] = (bf16_t)(__expf(v - sm[r]) * sz[r]);
    }
    __syncthreads();
    for (int r = ty; r < 32; r += 8) {
        const int t = t0 + r;
        dA[(long)t * S_ + s0 + tx] = (bf16_t)(__expf(tile[tx][r] - tm[r]) * tz[r]);
    }
}

// ---------------------------------------------------------------------------
extern "C" void kernel_launch(void* const* d_in, const int* in_sizes, int n_in,
                              void* d_out, int out_size, void* d_ws, size_t ws_size,
                              hipStream_t stream)
{
    const float* f1 = (const float*)d_in[0];   // [16,1024,1024] fp32
    const float* f2 = (const float*)d_in[1];   // [16,1024,1024] fp32
    const float* W  = (const float*)d_in[2];   // [1024,1024]    fp32

    float* out0 = (float*)d_out;               // final fp32 outputs
    float* out1 = out0 + (long)B_ * MAT_;

    // d_out reuse (regions fully dead before final overwrite):
    bf16_t* a1h = (bf16_t*)out0;               // 32 MB, dead after G2
    bf16_t* a1l = a1h + (long)B_ * MAT_;       // 32 MB, dead after G2
    bf16_t* Wth = (bf16_t*)out1;               //  2 MB, dead after G1
    bf16_t* Wtl = Wth + (long)MAT_;            //  2 MB, dead after G1
    float*  cc  = out1;                        // 64 MB fp32 logits, dead after build

    char* w = (char*)d_ws;                     // total ws use: ~130 MB
    bf16_t* f1h  = (bf16_t*)(w);               // 32 MB  (G1, dual)
    bf16_t* f2h  = (bf16_t*)(w + (32l << 20)); // 32 MB  (G2, dual)
    bf16_t* f1l  = (bf16_t*)(w + (64l << 20)); // 32 MB  (G1 only)
    bf16_t* f2l  = (bf16_t*)(w + (96l << 20)); // 32 MB  (G2 only)
    bf16_t* attA = f1l;                        // aliases f1l (dead after G1)
    bf16_t* attV = f2l;                        // aliases f2l (dead after G2)
    float*  Mp2  = (float*)(w + (128l << 20)); // [16][8][1024] partials
    float*  Zp2  = Mp2 + 16 * 8 * 1024;
    float*  Np2  = Zp2 + 16 * 8 * 1024;
    float*  Yp2  = Np2 + 16 * 8 * 1024;        // 2 MB total

    // 0. pre-split all fp32 operands to bf16 hi/lo + W transpose (one launch)
    split_all<<<33792, 256, 0, stream>>>(f1, f2, W, f1h, f1l, f2h, f2l, Wth, Wtl);

    // 1. a1 = f1 @ Wt^T (3-term split), bf16 hi/lo; bm-contiguous per XCD
    gemm8p<1, 1, 3, 0><<<dim3(8, 128, 1), 512, 0, stream>>>(
        f1h, f1l, Wth, Wtl, nullptr, a1h, a1l,
        nullptr, nullptr, nullptr, nullptr, BS_, 1024, 1024, 0, 0, 0);

    // 2. cc[b] = a1[b] @ f2[b]^T (3-term split) + in-epilogue softmax partials
    gemm8p<1, 0, 1, 1><<<dim3(8, 8, 16), 512, 0, stream>>>(
        a1h, a1l, f2h, f2l, cc, nullptr, nullptr,
        Mp2, Zp2, Np2, Yp2, 1024, 1024, 1024, MAT_, MAT_, MAT_);

    // 3. fused combine + attention-matrix build (one cc pass)
    build_atts<<<dim3(32, 32, 16), dim3(32, 8), 0, stream>>>(
        cc, Mp2, Zp2, Np2, Yp2, attA, attV);

    // 4. dual: out0[b] = attA^T[b] @ f1[b]^T ; out1[b] = attV^T[b] @ f2[b]^T
    gemm8p<0, 0, 2, 0><<<dim3(8, 8, 32), 512, 0, stream>>>(
        attA, attV, f1h, f2h, out0, nullptr, nullptr,
        nullptr, nullptr, nullptr, nullptr, 1024, 1024, 1024, MAT_, MAT_, MAT_);
}